// Round 10
// baseline (364.360 us; speedup 1.0000x reference)
//
#include <hip/hip_runtime.h>
#include <hip/hip_bf16.h>

#define HDIM 128
#define CDIM 8
#define SCAN_CHUNK 4096   // 256 threads x 16 elements

// Harness contract (pinned empirically, rounds 1-3):
//   float32 tensors -> const float* ; int64 edge_index -> const int* ; output -> float*
//
// R9 post-mortem: agg still ~74us with 0 bank conflicts and hbm 14% / VALU 23%
// -> latency-bound with ~2 outstanding loads/wave (4 edges per chain hop).
// R10: 16 edge-groups x 4 lanes; per iteration 16 edges via 4 INDEPENDENT
// 32-feature chunk gathers + prefetched srcW => ~5 loads in flight, avg node
// done in 1 iteration. acc = 32 floats/lane, shfl_xor(4/8/16/32) reduction.

// ---------- histogram ----------
__global__ void k_hist(const int* __restrict__ col, int* __restrict__ cnt, int E) {
    int e = blockIdx.x * blockDim.x + threadIdx.x;
    if (e < E) atomicAdd(&cnt[col[e]], 1);
}

// ---------- single-launch decoupled-lookback scan (13 co-resident blocks) ----------
__global__ __launch_bounds__(256) void k_scan(const int* __restrict__ cnt,
                                              int* __restrict__ status,
                                              int* __restrict__ ptr,
                                              int* __restrict__ cursor,
                                              float* __restrict__ dinv,
                                              int n, int Etot) {
    int b = blockIdx.x, tid = threadIdx.x;
    int base = b * SCAN_CHUNK + tid * 16;
    int v[16];
    int s = 0;
#pragma unroll
    for (int j = 0; j < 16; j++) {
        int i = base + j;
        v[j] = (i < n) ? cnt[i] : 0;
        s += v[j];
    }
    int lane = tid & 63, wid = tid >> 6;
    int x = s;
    for (int off = 1; off < 64; off <<= 1) {
        int y = __shfl_up(x, off, 64);
        if (lane >= off) x += y;
    }
    __shared__ int wtot[4];
    __shared__ int sprefix;
    if (lane == 63) wtot[wid] = x;
    __syncthreads();
    if (tid == 0) {
        int tot = wtot[0] + wtot[1] + wtot[2] + wtot[3];
        atomicExch(&status[b], tot + 1);            // publish first (no peer deadlock)
        int pre = 0;
        for (int p = 0; p < b; p++) {
            int vv;
            do { vv = atomicAdd(&status[p], 0); } while (vv == 0);
            pre += vv - 1;
        }
        sprefix = pre;
        if (b == 0) ptr[n] = Etot;
    }
    __syncthreads();
    int woff = 0;
    for (int w = 0; w < wid; w++) woff += wtot[w];
    int excl = sprefix + woff + (x - s);
#pragma unroll
    for (int j = 0; j < 16; j++) {
        int i = base + j;
        if (i < n) {
            ptr[i] = excl;
            cursor[i] = excl;
            dinv[i] = rsqrtf((float)v[j] + 1.0f);   // +1 self-loop
        }
        excl += v[j];
    }
}

// ---------- fused scatter | gemm, stripe-interleaved for co-residency ----------
__global__ __launch_bounds__(256) void k_scatter_gemm(const int* __restrict__ ei,
                                                      int* __restrict__ cursor,
                                                      int2* __restrict__ srcW, int E,
                                                      const float* __restrict__ dinv,
                                                      const float* __restrict__ X,
                                                      const float* __restrict__ W,
                                                      __hip_bfloat16* __restrict__ Y,
                                                      int nrows) {
    int tid = threadIdx.x;
    int q = blockIdx.x / 3, k3 = blockIdx.x % 3;
    if (k3 < 2) {
        int e = (2 * q + k3) * 256 + tid;
        if (e < E) {
            int c = ei[(size_t)E + e];   // target
            int r = ei[e];               // source
            int pos = atomicAdd(&cursor[c], 1);
            srcW[pos] = make_int2(r, __float_as_int(dinv[r]));
        }
    } else {
        __shared__ float xsh[32][HDIM];
        int c = tid & 127;
        int g = tid >> 7;
        int r0 = q * 32;
        for (int idx = tid; idx < 32 * HDIM / 4; idx += 256) {
            int row = idx >> 5;
            int kk = (idx & 31) * 4;
            int gr = r0 + row;
            float4 v = make_float4(0.f, 0.f, 0.f, 0.f);
            if (gr < nrows) v = *(const float4*)(X + (size_t)gr * HDIM + kk);
            *(float4*)&xsh[row][kk] = v;
        }
        __syncthreads();
        float acc[16];
#pragma unroll
        for (int r = 0; r < 16; r++) acc[r] = 0.f;
        for (int k4 = 0; k4 < HDIM / 4; k4++) {
            int k = k4 * 4;
            float w0 = W[(size_t)(k + 0) * HDIM + c];
            float w1 = W[(size_t)(k + 1) * HDIM + c];
            float w2 = W[(size_t)(k + 2) * HDIM + c];
            float w3 = W[(size_t)(k + 3) * HDIM + c];
#pragma unroll
            for (int r = 0; r < 16; r++) {
                float4 xv = *(const float4*)&xsh[g * 16 + r][k];
                acc[r] = fmaf(xv.x, w0, fmaf(xv.y, w1, fmaf(xv.z, w2, fmaf(xv.w, w3, acc[r]))));
            }
        }
#pragma unroll
        for (int r = 0; r < 16; r++) {
            int gr = r0 + g * 16 + r;
            if (gr < nrows) Y[(size_t)gr * HDIM + c] = __float2bfloat16(acc[r]);
        }
    }
}

// ---------- standalone GEMM (layer 2) ----------
__global__ __launch_bounds__(256) void k_gemm(const float* __restrict__ X,
                                              const float* __restrict__ W,
                                              __hip_bfloat16* __restrict__ Y, int nrows) {
    __shared__ float xsh[32][HDIM];
    int tid = threadIdx.x;
    int c = tid & 127;
    int g = tid >> 7;
    int r0 = blockIdx.x * 32;
    for (int idx = tid; idx < 32 * HDIM / 4; idx += 256) {
        int row = idx >> 5;
        int kk = (idx & 31) * 4;
        int gr = r0 + row;
        float4 v = make_float4(0.f, 0.f, 0.f, 0.f);
        if (gr < nrows) v = *(const float4*)(X + (size_t)gr * HDIM + kk);
        *(float4*)&xsh[row][kk] = v;
    }
    __syncthreads();
    float acc[16];
#pragma unroll
    for (int r = 0; r < 16; r++) acc[r] = 0.f;
    for (int k4 = 0; k4 < HDIM / 4; k4++) {
        int k = k4 * 4;
        float w0 = W[(size_t)(k + 0) * HDIM + c];
        float w1 = W[(size_t)(k + 1) * HDIM + c];
        float w2 = W[(size_t)(k + 2) * HDIM + c];
        float w3 = W[(size_t)(k + 3) * HDIM + c];
#pragma unroll
        for (int r = 0; r < 16; r++) {
            float4 xv = *(const float4*)&xsh[g * 16 + r][k];
            acc[r] = fmaf(xv.x, w0, fmaf(xv.y, w1, fmaf(xv.z, w2, fmaf(xv.w, w3, acc[r]))));
        }
    }
#pragma unroll
    for (int r = 0; r < 16; r++) {
        int gr = r0 + g * 16 + r;
        if (gr < nrows) Y[(size_t)gr * HDIM + c] = __float2bfloat16(acc[r]);
    }
}

// ---------- wave-per-node aggregation core, 16 edges/iteration ----------
// lane = (fs = lane&3, jg = lane>>4... NO: jg = lane>>2, 16 groups of 4).
// Group jg handles edges s+jg, s+jg+16, ...; lane-quad reads 64B lines.
// Per iteration: 4 independent chunk gathers (chunk c = features c*32..c*32+31;
// lane reads 16B at byte c*64 + fs*16 of its group's source row).
// acc[c][k] = partial sum of feature c*32 + fs*8 + k over group jg's edges.
// Butterfly shfl_xor(4,8,16,32) reduces across the 16 groups.
__device__ __forceinline__ void bf8_fma(uint4 qv, float w, float* acc) {
    unsigned u[4] = {qv.x, qv.y, qv.z, qv.w};
#pragma unroll
    for (int i = 0; i < 4; i++) {
        float lo = __uint_as_float(u[i] << 16);
        float hi = __uint_as_float(u[i] & 0xFFFF0000u);
        acc[2 * i]     = fmaf(w, lo, acc[2 * i]);
        acc[2 * i + 1] = fmaf(w, hi, acc[2 * i + 1]);
    }
}

__device__ __forceinline__ void agg_core16(const __hip_bfloat16* __restrict__ hin,
                                           const int* __restrict__ ptr,
                                           const int2* __restrict__ srcW,
                                           int node, int fs, int jg, float di,
                                           float acc[4][8]) {
#pragma unroll
    for (int c = 0; c < 4; c++)
#pragma unroll
        for (int k = 0; k < 8; k++) acc[c][k] = 0.f;

    if (jg == 0) {   // self-loop: 4 fs-lanes cover all 128 features
        const uint4* row = (const uint4*)(hin + (size_t)node * HDIM);
#pragma unroll
        for (int c = 0; c < 4; c++) bf8_fma(row[c * 4 + fs], di, acc[c]);
    }

    int s = ptr[node], e = ptr[node + 1];
    int iters = (e - s + 15) >> 4;
    int jj = s + jg;
    int2 p = (jj < e) ? srcW[jj] : make_int2(node, 0);
    for (int t = 0; t < iters; t++) {
        int2 cur = p;
        jj += 16;
        if (t + 1 < iters) p = (jj < e) ? srcW[jj] : make_int2(node, 0);   // prefetch
        const uint4* row = (const uint4*)(hin + (size_t)cur.x * HDIM);
        float w = __int_as_float(cur.y);
        uint4 q0 = row[0 * 4 + fs];   // 4 independent gathers in flight
        uint4 q1 = row[1 * 4 + fs];
        uint4 q2 = row[2 * 4 + fs];
        uint4 q3 = row[3 * 4 + fs];
        bf8_fma(q0, w, acc[0]);
        bf8_fma(q1, w, acc[1]);
        bf8_fma(q2, w, acc[2]);
        bf8_fma(q3, w, acc[3]);
    }
#pragma unroll
    for (int c = 0; c < 4; c++)
#pragma unroll
        for (int k = 0; k < 8; k++) {
            acc[c][k] += __shfl_xor(acc[c][k], 4, 64);
            acc[c][k] += __shfl_xor(acc[c][k], 8, 64);
            acc[c][k] += __shfl_xor(acc[c][k], 16, 64);
            acc[c][k] += __shfl_xor(acc[c][k], 32, 64);
        }
}

// ---------- agg layer 1: fp32 output rows ----------
__global__ __launch_bounds__(256) void k_agg(const __hip_bfloat16* __restrict__ hin,
                                             float* __restrict__ hout,
                                             const int* __restrict__ ptr,
                                             const int2* __restrict__ srcW,
                                             const float* __restrict__ dinv,
                                             const float* __restrict__ bias,
                                             int n) {
    int node = blockIdx.x * 4 + (threadIdx.x >> 6);
    if (node >= n) return;
    int lane = threadIdx.x & 63;
    int fs = lane & 3, jg = lane >> 2;
    float di = dinv[node];
    float acc[4][8];
    agg_core16(hin, ptr, srcW, node, fs, jg, di, acc);
    // lanes with jg==c store chunk c at their fs: 16 lanes x 8 floats = 128
#pragma unroll
    for (int c = 0; c < 4; c++) {
        if (jg == c) {
            const float4* b4 = (const float4*)(bias + c * 32 + fs * 8);
            float4 bb0 = b4[0], bb1 = b4[1];
            float4 v0 = make_float4(fmaf(di, acc[c][0], bb0.x), fmaf(di, acc[c][1], bb0.y),
                                    fmaf(di, acc[c][2], bb0.z), fmaf(di, acc[c][3], bb0.w));
            float4 v1 = make_float4(fmaf(di, acc[c][4], bb1.x), fmaf(di, acc[c][5], bb1.y),
                                    fmaf(di, acc[c][6], bb1.z), fmaf(di, acc[c][7], bb1.w));
            float4* o4 = (float4*)(hout + (size_t)node * HDIM + c * 32 + fs * 8);
            o4[0] = v0;
            o4[1] = v1;
        }
    }
}

// ---------- agg layer 2 + fused FC ----------
__global__ __launch_bounds__(256) void k_agg_fc(const __hip_bfloat16* __restrict__ hin,
                                                const int* __restrict__ ptr,
                                                const int2* __restrict__ srcW,
                                                const float* __restrict__ dinv,
                                                const float* __restrict__ bias,
                                                const float* __restrict__ Wfc,
                                                const float* __restrict__ bfc,
                                                float* __restrict__ out, int n) {
    int node = blockIdx.x * 4 + (threadIdx.x >> 6);
    if (node >= n) return;
    int lane = threadIdx.x & 63;
    int fs = lane & 3, jg = lane >> 2;
    float di = dinv[node];
    float acc[4][8];
    agg_core16(hin, ptr, srcW, node, fs, jg, di, acc);
    // h[c][k] = di*acc + bias for feature c*32 + fs*8 + k (all lanes)
    float hh[4][8];
#pragma unroll
    for (int c = 0; c < 4; c++) {
        const float4* b4 = (const float4*)(bias + c * 32 + fs * 8);
        float4 bb0 = b4[0], bb1 = b4[1];
        hh[c][0] = fmaf(di, acc[c][0], bb0.x); hh[c][1] = fmaf(di, acc[c][1], bb0.y);
        hh[c][2] = fmaf(di, acc[c][2], bb0.z); hh[c][3] = fmaf(di, acc[c][3], bb0.w);
        hh[c][4] = fmaf(di, acc[c][4], bb1.x); hh[c][5] = fmaf(di, acc[c][5], bb1.y);
        hh[c][6] = fmaf(di, acc[c][6], bb1.z); hh[c][7] = fmaf(di, acc[c][7], bb1.w);
    }
    // FC: col = jg&7; jg<8 handles chunks 0-1, jg>=8 chunks 2-3 (no double count).
    int col = jg & 7;
    int cbase = (jg < 8) ? 0 : 2;
    float pacc = 0.f;
#pragma unroll
    for (int cc = 0; cc < 2; cc++) {
        int c = cbase + cc;
        int f0 = c * 32 + fs * 8;
        float p0 = 0.f;
#pragma unroll
        for (int k = 0; k < 8; k++)
            p0 = fmaf((cc == 0 ? hh[cbase][k] : hh[cbase + 1][k]),
                      Wfc[(size_t)(f0 + k) * CDIM + col], p0);
        pacc += p0;
    }
    pacc += __shfl_xor(pacc, 1, 64);    // reduce fs
    pacc += __shfl_xor(pacc, 2, 64);
    pacc += __shfl_xor(pacc, 32, 64);   // combine chunk halves (jg vs jg+8)
    if (fs == 0 && jg < 8)
        out[(size_t)node * CDIM + col] = pacc + bfc[col];
}

extern "C" void kernel_launch(void* const* d_in, const int* in_sizes, int n_in,
                              void* d_out, int out_size, void* d_ws, size_t ws_size,
                              hipStream_t stream) {
    const float* x   = (const float*)d_in[0];
    const int*   ei  = (const int*)d_in[1];
    const float* W1  = (const float*)d_in[2];
    const float* b1  = (const float*)d_in[3];
    const float* W2  = (const float*)d_in[4];
    const float* b2  = (const float*)d_in[5];
    const float* Wfc = (const float*)d_in[6];
    const float* bfc = (const float*)d_in[7];
    float* out = (float*)d_out;

    const int N = in_sizes[0] / HDIM;   // 50000
    const int E = in_sizes[1] / 2;      // 800000
    const int B = (N + SCAN_CHUNK - 1) / SCAN_CHUNK;   // 13

    // workspace layout
    float*          bufF = (float*)d_ws;                                  // N*128 fp32
    __hip_bfloat16* bufH = (__hip_bfloat16*)(bufF + (size_t)N * HDIM);    // N*128 bf16
    float* dinv   = (float*)(bufH + (size_t)N * HDIM);  // N
    int*   cnt    = (int*)(dinv + N);                   // N      } zeroed together
    int*   status = cnt + N;                            // 16     }
    int*   ptr    = status + 16;                        // N+1
    int*   cursor = ptr + (N + 1);                      // N
    int2*  srcW   = (int2*)(((uintptr_t)(cursor + N) + 15) & ~(uintptr_t)15);  // E int2

    hipMemsetAsync(cnt, 0, (size_t)(N + 16) * sizeof(int), stream);
    k_hist<<<(E + 255) / 256, 256, 0, stream>>>(ei + E, cnt, E);
    k_scan<<<B, 256, 0, stream>>>(cnt, status, ptr, cursor, dinv, N, E);

    const int Gg = (N + 31) / 32;          // 1563 gemm blocks; 2*Gg=3126 >= 3125 scatter
    k_scatter_gemm<<<3 * Gg, 256, 0, stream>>>(ei, cursor, srcW, E, dinv, x, W1, bufH, N);

    k_agg<<<(N + 3) / 4, 256, 0, stream>>>(bufH, bufF, ptr, srcW, dinv, b1, N);
    k_gemm<<<Gg, 256, 0, stream>>>(bufF, W2, bufH, N);
    k_agg_fc<<<(N + 3) / 4, 256, 0, stream>>>(bufH, ptr, srcW, dinv, b2, Wfc, bfc, out, N);
}

// Round 11
// 327.750 us; speedup vs baseline: 1.1117x; 1.1117x over previous
//
#include <hip/hip_runtime.h>
#include <hip/hip_bf16.h>

#define HDIM 128
#define CDIM 8
#define SCAN_CHUNK 4096   // 256 threads x 16 elements

// Harness contract (pinned empirically, rounds 1-3):
//   float32 tensors -> const float* ; int64 edge_index -> const int* ; output -> float*
//
// R10 post-mortem: 16-group agg regressed (VGPR 48, occ 48%, 8x bigger shfl
// reduction) -- traded TLP for ILP ~1:1. Agg floor = LLC-hit latency x total
// outstanding loads. R11: R9 core (16fs x 4jg, VGPR-lean) + depth-2 edge
// pipeline (cheap ILP, stays under 64-VGPR cliff); fuse gemm2 into agg1 via
// LDS (kills 51MB bufF roundtrip + 1 launch). 6 dispatches.

// ---------- histogram ----------
__global__ void k_hist(const int* __restrict__ col, int* __restrict__ cnt, int E) {
    int e = blockIdx.x * blockDim.x + threadIdx.x;
    if (e < E) atomicAdd(&cnt[col[e]], 1);
}

// ---------- single-launch decoupled-lookback scan (13 co-resident blocks) ----------
__global__ __launch_bounds__(256) void k_scan(const int* __restrict__ cnt,
                                              int* __restrict__ status,
                                              int* __restrict__ ptr,
                                              int* __restrict__ cursor,
                                              float* __restrict__ dinv,
                                              int n, int Etot) {
    int b = blockIdx.x, tid = threadIdx.x;
    int base = b * SCAN_CHUNK + tid * 16;
    int v[16];
    int s = 0;
#pragma unroll
    for (int j = 0; j < 16; j++) {
        int i = base + j;
        v[j] = (i < n) ? cnt[i] : 0;
        s += v[j];
    }
    int lane = tid & 63, wid = tid >> 6;
    int x = s;
    for (int off = 1; off < 64; off <<= 1) {
        int y = __shfl_up(x, off, 64);
        if (lane >= off) x += y;
    }
    __shared__ int wtot[4];
    __shared__ int sprefix;
    if (lane == 63) wtot[wid] = x;
    __syncthreads();
    if (tid == 0) {
        int tot = wtot[0] + wtot[1] + wtot[2] + wtot[3];
        atomicExch(&status[b], tot + 1);            // publish first (no peer deadlock)
        int pre = 0;
        for (int p = 0; p < b; p++) {
            int vv;
            do { vv = atomicAdd(&status[p], 0); } while (vv == 0);
            pre += vv - 1;
        }
        sprefix = pre;
        if (b == 0) ptr[n] = Etot;
    }
    __syncthreads();
    int woff = 0;
    for (int w = 0; w < wid; w++) woff += wtot[w];
    int excl = sprefix + woff + (x - s);
#pragma unroll
    for (int j = 0; j < 16; j++) {
        int i = base + j;
        if (i < n) {
            ptr[i] = excl;
            cursor[i] = excl;
            dinv[i] = rsqrtf((float)v[j] + 1.0f);   // +1 self-loop
        }
        excl += v[j];
    }
}

// ---------- fused scatter | gemm, stripe-interleaved for co-residency ----------
__global__ __launch_bounds__(256) void k_scatter_gemm(const int* __restrict__ ei,
                                                      int* __restrict__ cursor,
                                                      int2* __restrict__ srcW, int E,
                                                      const float* __restrict__ dinv,
                                                      const float* __restrict__ X,
                                                      const float* __restrict__ W,
                                                      __hip_bfloat16* __restrict__ Y,
                                                      int nrows) {
    int tid = threadIdx.x;
    int q = blockIdx.x / 3, k3 = blockIdx.x % 3;
    if (k3 < 2) {
        int e = (2 * q + k3) * 256 + tid;
        if (e < E) {
            int c = ei[(size_t)E + e];   // target
            int r = ei[e];               // source
            int pos = atomicAdd(&cursor[c], 1);
            srcW[pos] = make_int2(r, __float_as_int(dinv[r]));
        }
    } else {
        __shared__ float xsh[32][HDIM];
        int c = tid & 127;
        int g = tid >> 7;
        int r0 = q * 32;
        for (int idx = tid; idx < 32 * HDIM / 4; idx += 256) {
            int row = idx >> 5;
            int kk = (idx & 31) * 4;
            int gr = r0 + row;
            float4 v = make_float4(0.f, 0.f, 0.f, 0.f);
            if (gr < nrows) v = *(const float4*)(X + (size_t)gr * HDIM + kk);
            *(float4*)&xsh[row][kk] = v;
        }
        __syncthreads();
        float acc[16];
#pragma unroll
        for (int r = 0; r < 16; r++) acc[r] = 0.f;
        for (int k4 = 0; k4 < HDIM / 4; k4++) {
            int k = k4 * 4;
            float w0 = W[(size_t)(k + 0) * HDIM + c];
            float w1 = W[(size_t)(k + 1) * HDIM + c];
            float w2 = W[(size_t)(k + 2) * HDIM + c];
            float w3 = W[(size_t)(k + 3) * HDIM + c];
#pragma unroll
            for (int r = 0; r < 16; r++) {
                float4 xv = *(const float4*)&xsh[g * 16 + r][k];
                acc[r] = fmaf(xv.x, w0, fmaf(xv.y, w1, fmaf(xv.z, w2, fmaf(xv.w, w3, acc[r]))));
            }
        }
#pragma unroll
        for (int r = 0; r < 16; r++) {
            int gr = r0 + g * 16 + r;
            if (gr < nrows) Y[(size_t)gr * HDIM + c] = __float2bfloat16(acc[r]);
        }
    }
}

// ---------- wave-per-node agg core: R9 layout (16 fs x 4 jg) + depth-2 pipeline ----------
// lane: fs = lane&15 owns features fs*8..fs*8+7 (one 16B uint4); jg = lane>>4
// is a 4-way edge split; group jg handles edge streams s+jg+8t and s+jg+4+8t.
// 2 srcW + 2 row gathers independent per iteration; acc stays 8 floats (VGPR-lean).
__device__ __forceinline__ void bf8_fma(uint4 qv, float w, float* acc) {
    unsigned u[4] = {qv.x, qv.y, qv.z, qv.w};
#pragma unroll
    for (int i = 0; i < 4; i++) {
        float lo = __uint_as_float(u[i] << 16);
        float hi = __uint_as_float(u[i] & 0xFFFF0000u);
        acc[2 * i]     = fmaf(w, lo, acc[2 * i]);
        acc[2 * i + 1] = fmaf(w, hi, acc[2 * i + 1]);
    }
}

__device__ __forceinline__ void agg_core(const __hip_bfloat16* __restrict__ hin,
                                         const int* __restrict__ ptr,
                                         const int2* __restrict__ srcW,
                                         int node, int fs, int jg, float di,
                                         float acc[8]) {
#pragma unroll
    for (int k = 0; k < 8; k++) acc[k] = 0.f;
    if (jg == 0) {   // self-loop, weight di (final di applied by caller)
        uint4 qv = ((const uint4*)(hin + (size_t)node * HDIM))[fs];
        bf8_fma(qv, di, acc);
    }
    int s = ptr[node], e = ptr[node + 1];
    int j0 = s + jg, j1 = s + jg + 4;
    int2 Z = make_int2(node, 0);          // weight 0: contributes nothing
    int2 p0 = (j0 < e) ? srcW[j0] : Z;
    int2 p1 = (j1 < e) ? srcW[j1] : Z;
    int iters = (e - s + 7) >> 3;
    for (int t = 0; t < iters; t++) {
        int2 c0 = p0, c1 = p1;
        j0 += 8; j1 += 8;
        if (t + 1 < iters) {              // prefetch next pair
            p0 = (j0 < e) ? srcW[j0] : Z;
            p1 = (j1 < e) ? srcW[j1] : Z;
        }
        uint4 q0 = ((const uint4*)(hin + (size_t)c0.x * HDIM))[fs];
        uint4 q1 = ((const uint4*)(hin + (size_t)c1.x * HDIM))[fs];
        bf8_fma(q0, __int_as_float(c0.y), acc);
        bf8_fma(q1, __int_as_float(c1.y), acc);
    }
#pragma unroll
    for (int k = 0; k < 8; k++) {
        acc[k] += __shfl_xor(acc[k], 16, 64);
        acc[k] += __shfl_xor(acc[k], 32, 64);
    }
}

// ---------- fused agg layer-1 + GEMM layer-2 ----------
// Block = 32 nodes: phase 1 = 4 waves x 8 nodes agg -> h1 rows into LDS (16KB);
// phase 2 = k_gemm structure reading X from LDS, W2 streamed, bf16 out.
__global__ __launch_bounds__(256) void k_agg_gemm(const __hip_bfloat16* __restrict__ hin,
                                                  __hip_bfloat16* __restrict__ hout,
                                                  const int* __restrict__ ptr,
                                                  const int2* __restrict__ srcW,
                                                  const float* __restrict__ dinv,
                                                  const float* __restrict__ bias,
                                                  const float* __restrict__ W2, int n) {
    __shared__ float xsh[32][HDIM];
    int tid = threadIdx.x;
    int w = tid >> 6, lane = tid & 63;
    int fs = lane & 15, jg = lane >> 4;
    int base = blockIdx.x * 32;

    for (int i = 0; i < 8; i++) {
        int lr = w * 8 + i;
        int node = base + lr;
        if (node < n) {
            float di = dinv[node];
            float acc[8];
            agg_core(hin, ptr, srcW, node, fs, jg, di, acc);
            if (jg == 0) {
                const float4* b4 = (const float4*)(bias + fs * 8);
                float4 bb0 = b4[0], bb1 = b4[1];
                float4 v0 = make_float4(fmaf(di, acc[0], bb0.x), fmaf(di, acc[1], bb0.y),
                                        fmaf(di, acc[2], bb0.z), fmaf(di, acc[3], bb0.w));
                float4 v1 = make_float4(fmaf(di, acc[4], bb1.x), fmaf(di, acc[5], bb1.y),
                                        fmaf(di, acc[6], bb1.z), fmaf(di, acc[7], bb1.w));
                *(float4*)&xsh[lr][fs * 8]     = v0;
                *(float4*)&xsh[lr][fs * 8 + 4] = v1;
            }
        } else if (jg == 0) {
            float4 z = make_float4(0.f, 0.f, 0.f, 0.f);
            *(float4*)&xsh[lr][fs * 8]     = z;
            *(float4*)&xsh[lr][fs * 8 + 4] = z;
        }
    }
    __syncthreads();

    int c = tid & 127, g = tid >> 7;
    float acc[16];
#pragma unroll
    for (int r = 0; r < 16; r++) acc[r] = 0.f;
    for (int k4 = 0; k4 < HDIM / 4; k4++) {
        int k = k4 * 4;
        float w0 = W2[(size_t)(k + 0) * HDIM + c];
        float w1 = W2[(size_t)(k + 1) * HDIM + c];
        float w2 = W2[(size_t)(k + 2) * HDIM + c];
        float w3 = W2[(size_t)(k + 3) * HDIM + c];
#pragma unroll
        for (int r = 0; r < 16; r++) {
            float4 xv = *(const float4*)&xsh[g * 16 + r][k];
            acc[r] = fmaf(xv.x, w0, fmaf(xv.y, w1, fmaf(xv.z, w2, fmaf(xv.w, w3, acc[r]))));
        }
    }
#pragma unroll
    for (int r = 0; r < 16; r++) {
        int gr = base + g * 16 + r;
        if (gr < n) hout[(size_t)gr * HDIM + c] = __float2bfloat16(acc[r]);
    }
}

// ---------- agg layer 2 + fused FC (R9 epilogue, new core) ----------
__global__ __launch_bounds__(256) void k_agg_fc(const __hip_bfloat16* __restrict__ hin,
                                                const int* __restrict__ ptr,
                                                const int2* __restrict__ srcW,
                                                const float* __restrict__ dinv,
                                                const float* __restrict__ bias,
                                                const float* __restrict__ Wfc,
                                                const float* __restrict__ bfc,
                                                float* __restrict__ out, int n) {
    int node = blockIdx.x * 4 + (threadIdx.x >> 6);
    if (node >= n) return;
    int lane = threadIdx.x & 63;
    int fs = lane & 15, jg = lane >> 4;
    float di = dinv[node];
    float acc[8];
    agg_core(hin, ptr, srcW, node, fs, jg, di, acc);
    // all lanes hold full sums for features fs*8..fs*8+7
    const float4* b4 = (const float4*)(bias + fs * 8);
    float4 bb0 = b4[0], bb1 = b4[1];
    float h[8];
    h[0] = fmaf(di, acc[0], bb0.x); h[1] = fmaf(di, acc[1], bb0.y);
    h[2] = fmaf(di, acc[2], bb0.z); h[3] = fmaf(di, acc[3], bb0.w);
    h[4] = fmaf(di, acc[4], bb1.x); h[5] = fmaf(di, acc[5], bb1.y);
    h[6] = fmaf(di, acc[6], bb1.z); h[7] = fmaf(di, acc[7], bb1.w);
    // FC: lane covers outputs c0=2*jg, c0+1 over its 8 features; Wfc 4KB L1-hot
    int c0 = jg * 2;
    float p0 = 0.f, p1 = 0.f;
#pragma unroll
    for (int k = 0; k < 8; k++) {
        const float* wr = Wfc + (size_t)(fs * 8 + k) * CDIM + c0;
        p0 = fmaf(h[k], wr[0], p0);
        p1 = fmaf(h[k], wr[1], p1);
    }
#pragma unroll
    for (int off = 1; off < 16; off <<= 1) {
        p0 += __shfl_xor(p0, off, 64);
        p1 += __shfl_xor(p1, off, 64);
    }
    if (fs == 0) {
        out[(size_t)node * CDIM + c0]     = p0 + bfc[c0];
        out[(size_t)node * CDIM + c0 + 1] = p1 + bfc[c0 + 1];
    }
}

extern "C" void kernel_launch(void* const* d_in, const int* in_sizes, int n_in,
                              void* d_out, int out_size, void* d_ws, size_t ws_size,
                              hipStream_t stream) {
    const float* x   = (const float*)d_in[0];
    const int*   ei  = (const int*)d_in[1];
    const float* W1  = (const float*)d_in[2];
    const float* b1  = (const float*)d_in[3];
    const float* W2  = (const float*)d_in[4];
    const float* b2  = (const float*)d_in[5];
    const float* Wfc = (const float*)d_in[6];
    const float* bfc = (const float*)d_in[7];
    float* out = (float*)d_out;

    const int N = in_sizes[0] / HDIM;   // 50000
    const int E = in_sizes[1] / 2;      // 800000
    const int B = (N + SCAN_CHUNK - 1) / SCAN_CHUNK;   // 13

    // workspace layout (~33 MB)
    __hip_bfloat16* bufH  = (__hip_bfloat16*)d_ws;                       // N*128 bf16
    __hip_bfloat16* bufH2 = bufH + (size_t)N * HDIM;                     // N*128 bf16
    float* dinv   = (float*)(bufH2 + (size_t)N * HDIM);  // N
    int*   cnt    = (int*)(dinv + N);                    // N      } zeroed together
    int*   status = cnt + N;                             // 16     }
    int*   ptr    = status + 16;                         // N+1
    int*   cursor = ptr + (N + 1);                       // N
    int2*  srcW   = (int2*)(((uintptr_t)(cursor + N) + 15) & ~(uintptr_t)15);  // E int2

    hipMemsetAsync(cnt, 0, (size_t)(N + 16) * sizeof(int), stream);
    k_hist<<<(E + 255) / 256, 256, 0, stream>>>(ei + E, cnt, E);
    k_scan<<<B, 256, 0, stream>>>(cnt, status, ptr, cursor, dinv, N, E);

    const int Gg = (N + 31) / 32;          // 1563 gemm blocks; 2*Gg=3126 >= 3125 scatter
    k_scatter_gemm<<<3 * Gg, 256, 0, stream>>>(ei, cursor, srcW, E, dinv, x, W1, bufH, N);

    k_agg_gemm<<<Gg, 256, 0, stream>>>(bufH, bufH2, ptr, srcW, dinv, b1, W2, N);
    k_agg_fc<<<(N + 3) / 4, 256, 0, stream>>>(bufH2, ptr, srcW, dinv, b2, Wfc, bfc, out, N);
}